// Round 7
// baseline (279.780 us; speedup 1.0000x reference)
//
#include <hip/hip_runtime.h>

#define NCV 100000
#define NTV 300000
#define NPV 50000
#define OUTC 10
#define EMV 300000
#define EIV 600000
#define YST 16   // y_c / y_p row stride (floats) -> 64B-aligned rows

// ---------------- K0: per-column weight folding (blocks 0..9) + heads init (blocks 10+) ----
// Column o of: T1=Wn10@Wout, T2=Wn12@Wout, T3=0.5*(Wr10+Wr12)@Wout (128 each, LDS)
//             Q1=Wn01@T1 Q2=Wr01@T1 Q3=Wn03@T2 Q4=Wr03@T2 Q5=Wn00@T3 Q6=Wn02@T3 Q7=(Wr00+Wr02)@T3
//             B[:,o]: 45 entries (0..16 B_c | 17..33 B_p | 34..41 B_t | 42 u_c | 43 u_p | 44 k)
__global__ __launch_bounds__(256) void fold_heads(
    const float* __restrict__ Wcol, const float* __restrict__ bcol,
    const float* __restrict__ Wn, const float* __restrict__ Wr,
    const float* __restrict__ b_lin, const float* __restrict__ Wout,
    const float* __restrict__ bout,
    int* __restrict__ heads, int nheads, float* __restrict__ B) {
  int tid = threadIdx.x;
  if (blockIdx.x >= 10) {   // heads init to -1
    int i = (blockIdx.x - 10) * 256 + tid;
    int stride = (gridDim.x - 10) * 256;
    for (; i < nheads; i += stride) heads[i] = -1;
    return;
  }
  __shared__ float sWo[128];
  __shared__ float sT[3][128];
  __shared__ float sQ[7][128];
  const int o = blockIdx.x;
  if (tid < 128) sWo[tid] = Wout[tid * 10 + o];
  __syncthreads();

  const float* Wn00 = Wn;               const float* Wn01 = Wn + 16384;
  const float* Wn02 = Wn + 2 * 16384;   const float* Wn03 = Wn + 3 * 16384;
  const float* Wn10 = Wn + 4 * 16384;   const float* Wn12 = Wn + 6 * 16384;
  const float* Wr00 = Wr;               const float* Wr01 = Wr + 16384;
  const float* Wr02 = Wr + 2 * 16384;   const float* Wr03 = Wr + 3 * 16384;
  const float* Wr10 = Wr + 4 * 16384;   const float* Wr12 = Wr + 6 * 16384;

  // ---- T phase: 3 mats x 128 rows, one dot(128) per task ----
  for (int task = tid; task < 384; task += 256) {
    int mat = task >> 7, n = task & 127;
    float acc = 0.f;
    if (mat == 0) {
      const float4* w = (const float4*)(Wn10 + n * 128);
      for (int m = 0; m < 32; ++m) {
        float4 w4 = w[m];
        acc += w4.x * sWo[4 * m] + w4.y * sWo[4 * m + 1] +
               w4.z * sWo[4 * m + 2] + w4.w * sWo[4 * m + 3];
      }
    } else if (mat == 1) {
      const float4* w = (const float4*)(Wn12 + n * 128);
      for (int m = 0; m < 32; ++m) {
        float4 w4 = w[m];
        acc += w4.x * sWo[4 * m] + w4.y * sWo[4 * m + 1] +
               w4.z * sWo[4 * m + 2] + w4.w * sWo[4 * m + 3];
      }
    } else {
      const float4* wa = (const float4*)(Wr10 + n * 128);
      const float4* wb = (const float4*)(Wr12 + n * 128);
      for (int m = 0; m < 32; ++m) {
        float4 a = wa[m], b = wb[m];
        acc += 0.5f * ((a.x + b.x) * sWo[4 * m] + (a.y + b.y) * sWo[4 * m + 1] +
                       (a.z + b.z) * sWo[4 * m + 2] + (a.w + b.w) * sWo[4 * m + 3]);
      }
    }
    sT[mat][n] = acc;
  }
  __syncthreads();

  // ---- Q phase: 7 mats x 128 rows ----
  for (int task = tid; task < 896; task += 256) {
    int q = task / 128, k = task & 127;
    const float* Tc = sT[q < 2 ? 0 : (q < 4 ? 1 : 2)];
    const float4* w; const float4* w2 = nullptr;
    switch (q) {
      case 0: w = (const float4*)(Wn01 + k * 128); break;
      case 1: w = (const float4*)(Wr01 + k * 128); break;
      case 2: w = (const float4*)(Wn03 + k * 128); break;
      case 3: w = (const float4*)(Wr03 + k * 128); break;
      case 4: w = (const float4*)(Wn00 + k * 128); break;
      case 5: w = (const float4*)(Wn02 + k * 128); break;
      default: w = (const float4*)(Wr00 + k * 128); w2 = (const float4*)(Wr02 + k * 128); break;
    }
    float acc = 0.f;
    for (int n = 0; n < 32; ++n) {
      float4 w4 = w[n];
      if (w2) { float4 b = w2[n]; w4.x += b.x; w4.y += b.y; w4.z += b.z; w4.w += b.w; }
      acc += w4.x * Tc[4 * n] + w4.y * Tc[4 * n + 1] +
             w4.z * Tc[4 * n + 2] + w4.w * Tc[4 * n + 3];
    }
    sQ[q][k] = acc;
  }
  __syncthreads();

  // ---- B phase: 45 rows of column o ----
  if (tid < 45) {
    int r = tid;
    const float* WcC = Wcol, *WcT = Wcol + 128, *WcP = Wcol + 256;
    const float* bC = bcol, *bT = bcol + 128, *bP = bcol + 256;
    const float* b00 = b_lin, *b01 = b_lin + 128, *b02 = b_lin + 256, *b03 = b_lin + 384;
    const float* b10 = b_lin + 512, *b12 = b_lin + 768;
    float s = 0.f;
    if (r < 8) {
      for (int j = 0; j < 16; ++j) s += WcT[r * 16 + j] * sQ[0][r * 16 + j];
    } else if (r < 16) {
      int jr = r - 8;
      for (int j = 0; j < 16; ++j)
        s += WcC[jr * 16 + j] * (sQ[1][jr * 16 + j] + sQ[4][jr * 16 + j]);
    } else if (r == 16) {
      for (int k = 0; k < 128; ++k) s += bT[k] * sQ[0][k];
    } else if (r < 25) {
      int jr = r - 17;
      for (int j = 0; j < 16; ++j) s += WcT[jr * 16 + j] * sQ[2][jr * 16 + j];
    } else if (r < 33) {
      int jr = r - 25;
      for (int j = 0; j < 16; ++j)
        s += WcP[jr * 16 + j] * (sQ[3][jr * 16 + j] + sQ[5][jr * 16 + j]);
    } else if (r == 33) {
      for (int k = 0; k < 128; ++k) s += bT[k] * sQ[2][k];
    } else if (r < 42) {
      int jr = r - 34;
      for (int j = 0; j < 16; ++j) s += WcT[jr * 16 + j] * sQ[6][jr * 16 + j];
    } else if (r == 42) {
      for (int k = 0; k < 128; ++k)
        s += bC[k] * (sQ[1][k] + sQ[4][k]) + b01[k] * sT[0][k];
    } else if (r == 43) {
      for (int k = 0; k < 128; ++k)
        s += bP[k] * (sQ[3][k] + sQ[5][k]) + b03[k] * sT[1][k];
    } else {
      for (int n = 0; n < 128; ++n)
        s += (b10[n] + b12[n]) * sWo[n] + bT[n] * sQ[6][n] + (b00[n] + b02[n]) * sT[2][n];
    }
    float v = s * 0.5f;
    if (r == 44) v += bout[o];
    B[r * 10 + o] = v;
  }
}

// ---------------- K1: build 4 linked lists with int2 nodes {next, endpoint} ----------
// All node writes coalesced at own index e (14.4 MB total).
// t-side heads interleaved: heads_t[2t] = makes-list, heads_t[2t+1] = in-list.
__global__ __launch_bounds__(256) void build_graph(
    const int* __restrict__ ems, const int* __restrict__ emd,
    const int* __restrict__ eis, const int* __restrict__ eid,
    int* __restrict__ head_c, int* __restrict__ head_p,
    int* __restrict__ heads_t,
    int2* __restrict__ cn_m, int2* __restrict__ tn_m,
    int2* __restrict__ pn_i, int2* __restrict__ tn_i) {
  int e = blockIdx.x * 256 + threadIdx.x;
  if (e < EMV) {
    int c = ems[e], t = emd[e];
    int cn = atomicExch(&head_c[c], e);
    int tn = atomicExch(&heads_t[2 * t], e);
    cn_m[e] = make_int2(cn, t);
    tn_m[e] = make_int2(tn, c);
  }
  if (e < EIV) {
    int p = eis[e], t = eid[e];
    int pn = atomicExch(&head_p[p], e);
    int tn = atomicExch(&heads_t[2 * t + 1], e);
    pn_i[e] = make_int2(pn, t);
    tn_i[e] = make_int2(tn, p);
  }
}

// ---------------- K2: walk c/p int2 lists (2 random lines/edge), project y -----------
// z = [g*mean_xt, x_own, g] @ B -> 10 floats; y rows written coalesced (full 64B lines).
__global__ __launch_bounds__(256) void gather_y(
    const float* __restrict__ xt,
    const int* __restrict__ head_c, const int* __restrict__ head_p,
    const int2* __restrict__ cn_m, const int2* __restrict__ pn_i,
    const float* __restrict__ xc, const float* __restrict__ xp,
    const float* __restrict__ B,
    float* __restrict__ y_c, float* __restrict__ y_p) {
  __shared__ float sB[340];   // rows 0..33 of B
  int tid = threadIdx.x;
  for (int i = tid; i < 340; i += 256) sB[i] = B[i];
  __syncthreads();
  int i = blockIdx.x * 256 + tid;
  if (i >= NCV + NPV) return;
  bool isC = i < NCV;
  int idx = isC ? i : i - NCV;
  const int2* nodes = isC ? cn_m : pn_i;
  int e = isC ? head_c[idx] : head_p[idx];

  float acc[8] = {0.f, 0.f, 0.f, 0.f, 0.f, 0.f, 0.f, 0.f};
  float cnt = 0.f;
  while (e >= 0) {
    int2 v = nodes[e];
    const float4* xr = (const float4*)(xt + (size_t)v.y * 8);
    float4 u = xr[0], w = xr[1];
    acc[0] += u.x; acc[1] += u.y; acc[2] += u.z; acc[3] += u.w;
    acc[4] += w.x; acc[5] += w.y; acc[6] += w.z; acc[7] += w.w;
    cnt += 1.f;
    e = v.x;
  }

  const float* xo = (isC ? xc : xp) + (size_t)idx * 8;
  const float* Bs = sB + (isC ? 0 : 170);
  float gg = cnt > 0.f ? 1.f : 0.f;
  float inv = gg / fmaxf(cnt, 1.f);
  float lg[OUTC];
  #pragma unroll
  for (int o = 0; o < OUTC; ++o) lg[o] = gg * Bs[16 * 10 + o];
  #pragma unroll
  for (int r = 0; r < 8; ++r) {
    float zb = acc[r] * inv;
    float zo = xo[r];
    #pragma unroll
    for (int o = 0; o < OUTC; ++o)
      lg[o] += zb * Bs[r * 10 + o] + zo * Bs[(8 + r) * 10 + o];
  }
  float4* yv = (float4*)((isC ? y_c : y_p) + (size_t)idx * YST);
  yv[0] = make_float4(lg[0], lg[1], lg[2], lg[3]);
  yv[1] = make_float4(lg[4], lg[5], lg[6], lg[7]);
  yv[2] = make_float4(lg[8], lg[9], 0.f, 0.f);
  yv[3] = make_float4(0.f, 0.f, 0.f, 0.f);
}

// ---------------- K3: dual interleaved int2 walks + LLC-resident y reads + softmax ----
__global__ __launch_bounds__(256) void gather_t(
    const float* __restrict__ y_c, const float* __restrict__ y_p,
    const float* __restrict__ xt,
    const int* __restrict__ heads_t,
    const int2* __restrict__ tn_m, const int2* __restrict__ tn_i,
    const float* __restrict__ B, float* __restrict__ out) {
  __shared__ float sB[110];   // rows 34..44 of B
  int tid = threadIdx.x;
  for (int i = tid; i < 110; i += 256) sB[i] = B[340 + i];
  __syncthreads();
  int t = blockIdx.x * 256 + tid;
  if (t >= NTV) return;

  int2 ht = ((const int2*)heads_t)[t];   // {makes-head, in-head}, one 8B coalesced load
  int e1 = ht.x, e2 = ht.y;

  float sc[OUTC] = {0.f, 0.f, 0.f, 0.f, 0.f, 0.f, 0.f, 0.f, 0.f, 0.f};
  float sp[OUTC] = {0.f, 0.f, 0.f, 0.f, 0.f, 0.f, 0.f, 0.f, 0.f, 0.f};
  float dc = 0.f, dp = 0.f;
  while (e1 >= 0 || e2 >= 0) {
    if (e1 >= 0) {
      int2 v = tn_m[e1];
      const float* yr = y_c + (size_t)v.y * YST;
      float4 u = *(const float4*)yr;
      float4 w = *(const float4*)(yr + 4);
      float2 z = *(const float2*)(yr + 8);
      sc[0] += u.x; sc[1] += u.y; sc[2] += u.z; sc[3] += u.w;
      sc[4] += w.x; sc[5] += w.y; sc[6] += w.z; sc[7] += w.w;
      sc[8] += z.x; sc[9] += z.y;
      dc += 1.f;
      e1 = v.x;
    }
    if (e2 >= 0) {
      int2 v = tn_i[e2];
      const float* yr = y_p + (size_t)v.y * YST;
      float4 u = *(const float4*)yr;
      float4 w = *(const float4*)(yr + 4);
      float2 z = *(const float2*)(yr + 8);
      sp[0] += u.x; sp[1] += u.y; sp[2] += u.z; sp[3] += u.w;
      sp[4] += w.x; sp[5] += w.y; sp[6] += w.z; sp[7] += w.w;
      sp[8] += z.x; sp[9] += z.y;
      dp += 1.f;
      e2 = v.x;
    }
  }

  float Gc = dc > 0.f ? 1.f : 0.f, Gp = dp > 0.f ? 1.f : 0.f;
  float ivc = 1.f / fmaxf(dc, 1.f), ivp = 1.f / fmaxf(dp, 1.f);

  const float4* xp4 = (const float4*)(xt + (size_t)t * 8);
  float4 xa = xp4[0], xb = xp4[1];
  float xv[8] = {xa.x, xa.y, xa.z, xa.w, xb.x, xb.y, xb.z, xb.w};

  float lg[OUTC];
  #pragma unroll
  for (int o = 0; o < OUTC; ++o)
    lg[o] = sc[o] * ivc + sp[o] * ivp +
            Gc * sB[80 + o] + Gp * sB[90 + o] + sB[100 + o];
  #pragma unroll
  for (int r = 0; r < 8; ++r) {
    float xr = xv[r];
    #pragma unroll
    for (int o = 0; o < OUTC; ++o) lg[o] += xr * sB[r * 10 + o];
  }

  float m = lg[0];
  #pragma unroll
  for (int o = 1; o < OUTC; ++o) m = fmaxf(m, lg[o]);
  float s = 0.f;
  #pragma unroll
  for (int o = 0; o < OUTC; ++o) { lg[o] = __expf(lg[o] - m); s += lg[o]; }
  float invs = 1.0f / s;
  float* op = &out[(size_t)t * OUTC];
  #pragma unroll
  for (int o = 0; o < 5; ++o) {
    float2 p2; p2.x = lg[2 * o] * invs; p2.y = lg[2 * o + 1] * invs;
    *(float2*)&op[2 * o] = p2;
  }
}

extern "C" void kernel_launch(void* const* d_in, const int* in_sizes, int n_in,
                              void* d_out, int out_size, void* d_ws, size_t ws_size,
                              hipStream_t stream) {
  const float* x_c   = (const float*)d_in[0];
  const float* x_t   = (const float*)d_in[1];
  const float* x_p   = (const float*)d_in[2];
  const float* W_col = (const float*)d_in[3];
  const float* b_col = (const float*)d_in[4];
  const float* Wn    = (const float*)d_in[5];
  const float* Wr    = (const float*)d_in[6];
  const float* b_lin = (const float*)d_in[7];
  const float* W_out = (const float*)d_in[8];
  const float* b_out = (const float*)d_in[9];
  const int* e_m_src = (const int*)d_in[10];
  const int* e_m_dst = (const int*)d_in[11];
  const int* e_i_src = (const int*)d_in[12];
  const int* e_i_dst = (const int*)d_in[13];
  float* out = (float*)d_out;

  // ---- workspace carve-out (~27 MB; ws_size = 256 MiB) ----
  size_t cursor = 0;
  char* base = (char*)d_ws;
  auto alloc = [&](size_t bytes) {
    void* p = base + cursor;
    cursor += (bytes + 255) & ~(size_t)255;
    return p;
  };
  int nheads = NCV + NPV + 2 * NTV;
  int* heads   = (int*)alloc((size_t)nheads * 4);                  // 3.0 MB
  int* head_c  = heads;
  int* head_p  = heads + NCV;
  int* heads_t = heads + NCV + NPV;                                // int2-interleaved per t
  int2* cn_m = (int2*)alloc((size_t)EMV * 8);                      // 2.4 MB
  int2* tn_m = (int2*)alloc((size_t)EMV * 8);                      // 2.4 MB
  int2* pn_i = (int2*)alloc((size_t)EIV * 8);                      // 4.8 MB
  int2* tn_i = (int2*)alloc((size_t)EIV * 8);                      // 4.8 MB
  float* y_c = (float*)alloc((size_t)NCV * YST * 4);               // 6.4 MB
  float* y_p = (float*)alloc((size_t)NPV * YST * 4);               // 3.2 MB
  float* B   = (float*)alloc(450 * 4);

  // ---- K0: fused per-column folding (blocks 0..9) + heads init (blocks 10..127) ----
  fold_heads<<<128, 256, 0, stream>>>(
      W_col, b_col, Wn, Wr, b_lin, W_out, b_out, heads, nheads, B);

  // ---- K1: build int2-node lists ----
  build_graph<<<(EIV + 255) / 256, 256, 0, stream>>>(
      e_m_src, e_m_dst, e_i_src, e_i_dst,
      head_c, head_p, heads_t, cn_m, tn_m, pn_i, tn_i);

  // ---- K2: gather x_t over c/p lists + project y ----
  gather_y<<<(NCV + NPV + 255) / 256, 256, 0, stream>>>(
      x_t, head_c, head_p, cn_m, pn_i, x_c, x_p, B, y_c, y_p);

  // ---- K3: gather y over t lists + combine + softmax ----
  gather_t<<<(NTV + 255) / 256, 256, 0, stream>>>(
      y_c, y_p, x_t, heads_t, tn_m, tn_i, B, out);
}

// Round 8
// 236.537 us; speedup vs baseline: 1.1828x; 1.1828x over previous
//
#include <hip/hip_runtime.h>

#define NCV 100000
#define NTV 300000
#define NPV 50000
#define DD 128
#define OUTC 10
#define EMV 300000
#define EIV 600000
#define YST 16   // y_c / y_p row stride (floats) -> 64B-aligned rows

// ---------------- weight folding (wave-per-output, shuffle reduce; proven r1) --------
// T1 = Wn10@Wout, T2 = Wn12@Wout, T3 = 0.5*(Wr10+Wr12)@Wout  (each 128x10)
__global__ __launch_bounds__(256) void prep_T_w(
    const float* __restrict__ Wn10, const float* __restrict__ Wn12,
    const float* __restrict__ Wr10, const float* __restrict__ Wr12,
    const float* __restrict__ Wout, float* __restrict__ T) {
  int gw = (blockIdx.x * 256 + threadIdx.x) >> 6;
  int lane = threadIdx.x & 63;
  if (gw >= 3 * 1280) return;
  int mat = gw / 1280, r = gw % 1280, n = r / 10, o = r % 10;
  float s = 0.f;
  #pragma unroll
  for (int mi = 0; mi < 2; ++mi) {
    int m = lane + mi * 64;
    float w;
    if (mat == 0) w = Wn10[n * 128 + m];
    else if (mat == 1) w = Wn12[n * 128 + m];
    else w = 0.5f * (Wr10[n * 128 + m] + Wr12[n * 128 + m]);
    s += w * Wout[m * 10 + o];
  }
  #pragma unroll
  for (int d = 32; d; d >>= 1) s += __shfl_xor(s, d);
  if (lane == 0) T[gw] = s;
}

// Q1=Wn01@T1 Q2=Wr01@T1 Q3=Wn03@T2 Q4=Wr03@T2 Q5=Wn00@T3 Q6=Wn02@T3 Q7=(Wr00+Wr02)@T3
__global__ __launch_bounds__(256) void prep_Q_w(
    const float* __restrict__ Wn01, const float* __restrict__ Wr01,
    const float* __restrict__ Wn03, const float* __restrict__ Wr03,
    const float* __restrict__ Wn00, const float* __restrict__ Wn02,
    const float* __restrict__ Wr00, const float* __restrict__ Wr02,
    const float* __restrict__ T, float* __restrict__ Q) {
  int gw = (blockIdx.x * 256 + threadIdx.x) >> 6;
  int lane = threadIdx.x & 63;
  if (gw >= 7 * 1280) return;
  int q = gw / 1280, r = gw % 1280, k = r / 10, o = r % 10;
  const float* T1 = T, *T2 = T + 1280, *T3 = T + 2560;
  float s = 0.f;
  #pragma unroll
  for (int ni = 0; ni < 2; ++ni) {
    int n = lane + ni * 64;
    float w, t;
    switch (q) {
      case 0: w = Wn01[k * 128 + n]; t = T1[n * 10 + o]; break;
      case 1: w = Wr01[k * 128 + n]; t = T1[n * 10 + o]; break;
      case 2: w = Wn03[k * 128 + n]; t = T2[n * 10 + o]; break;
      case 3: w = Wr03[k * 128 + n]; t = T2[n * 10 + o]; break;
      case 4: w = Wn00[k * 128 + n]; t = T3[n * 10 + o]; break;
      case 5: w = Wn02[k * 128 + n]; t = T3[n * 10 + o]; break;
      default: w = Wr00[k * 128 + n] + Wr02[k * 128 + n]; t = T3[n * 10 + o]; break;
    }
    s += w * t;
  }
  #pragma unroll
  for (int d = 32; d; d >>= 1) s += __shfl_xor(s, d);
  if (lane == 0) Q[gw] = s;
}

// Final 45x10 coefficient table B (rows: 0..16 B_c | 17..33 B_p | 34..41 B_t |
// 42 u_c | 43 u_p | 44 k). Uniform outer 0.5; bout added to row 44.
__global__ __launch_bounds__(256) void prep_B_w(
    const float* __restrict__ Wcol, const float* __restrict__ bcol,
    const float* __restrict__ b_lin, const float* __restrict__ Wout,
    const float* __restrict__ bout, const float* __restrict__ T,
    const float* __restrict__ Q, float* __restrict__ B) {
  int gw = (blockIdx.x * 256 + threadIdx.x) >> 6;
  int lane = threadIdx.x & 63;
  if (gw >= 450) return;
  int r = gw / 10, o = gw % 10;
  const float* WcC = Wcol, *WcT = Wcol + 128, *WcP = Wcol + 256;
  const float* bC = bcol, *bT = bcol + 128, *bP = bcol + 256;
  const float* Q1 = Q, *Q2 = Q + 1280, *Q3 = Q + 2560, *Q4 = Q + 3840;
  const float* Q5 = Q + 5120, *Q6 = Q + 6400, *Q7 = Q + 7680;
  const float* T1 = T, *T2 = T + 1280, *T3 = T + 2560;
  const float* b00 = b_lin, *b01 = b_lin + 128, *b02 = b_lin + 256, *b03 = b_lin + 384;
  const float* b10 = b_lin + 512, *b12 = b_lin + 768;
  float s = 0.f;
  if (r < 8) {
    if (lane < 16) s = WcT[r * 16 + lane] * Q1[(r * 16 + lane) * 10 + o];
  } else if (r < 16) {
    int j = r - 8;
    if (lane < 16)
      s = WcC[j * 16 + lane] * (Q2[(j * 16 + lane) * 10 + o] + Q5[(j * 16 + lane) * 10 + o]);
  } else if (r == 16) {
    for (int k2 = lane; k2 < 128; k2 += 64) s += bT[k2] * Q1[k2 * 10 + o];
  } else if (r < 25) {
    int j = r - 17;
    if (lane < 16) s = WcT[j * 16 + lane] * Q3[(j * 16 + lane) * 10 + o];
  } else if (r < 33) {
    int j = r - 25;
    if (lane < 16)
      s = WcP[j * 16 + lane] * (Q4[(j * 16 + lane) * 10 + o] + Q6[(j * 16 + lane) * 10 + o]);
  } else if (r == 33) {
    for (int k2 = lane; k2 < 128; k2 += 64) s += bT[k2] * Q3[k2 * 10 + o];
  } else if (r < 42) {
    int j = r - 34;
    if (lane < 16) s = WcT[j * 16 + lane] * Q7[(j * 16 + lane) * 10 + o];
  } else if (r == 42) {
    for (int k2 = lane; k2 < 128; k2 += 64)
      s += bC[k2] * (Q2[k2 * 10 + o] + Q5[k2 * 10 + o]) + b01[k2] * T1[k2 * 10 + o];
  } else if (r == 43) {
    for (int k2 = lane; k2 < 128; k2 += 64)
      s += bP[k2] * (Q4[k2 * 10 + o] + Q6[k2 * 10 + o]) + b03[k2] * T2[k2 * 10 + o];
  } else {
    for (int n = lane; n < 128; n += 64)
      s += (b10[n] + b12[n]) * Wout[n * 10 + o] + bT[n] * Q7[n * 10 + o] +
           (b00[n] + b02[n]) * T3[n * 10 + o];
  }
  #pragma unroll
  for (int d = 32; d; d >>= 1) s += __shfl_xor(s, d);
  if (lane == 0) {
    float v = s * 0.5f;
    if (r == 44) v += bout[o];
    B[gw] = v;
  }
}

// ---------------- K1: build 4 linked lists with int2 nodes {next, endpoint} ----------
// All node writes coalesced at own index e (14.4 MB total).
// t-side heads interleaved: heads_t[2t] = makes-list, heads_t[2t+1] = in-list.
__global__ __launch_bounds__(256) void build_graph(
    const int* __restrict__ ems, const int* __restrict__ emd,
    const int* __restrict__ eis, const int* __restrict__ eid,
    int* __restrict__ head_c, int* __restrict__ head_p,
    int* __restrict__ heads_t,
    int2* __restrict__ cn_m, int2* __restrict__ tn_m,
    int2* __restrict__ pn_i, int2* __restrict__ tn_i) {
  int e = blockIdx.x * 256 + threadIdx.x;
  if (e < EMV) {
    int c = ems[e], t = emd[e];
    int cn = atomicExch(&head_c[c], e);
    int tn = atomicExch(&heads_t[2 * t], e);
    cn_m[e] = make_int2(cn, t);
    tn_m[e] = make_int2(tn, c);
  }
  if (e < EIV) {
    int p = eis[e], t = eid[e];
    int pn = atomicExch(&head_p[p], e);
    int tn = atomicExch(&heads_t[2 * t + 1], e);
    pn_i[e] = make_int2(pn, t);
    tn_i[e] = make_int2(tn, p);
  }
}

// ---------------- K2: walk c/p int2 lists (2 random lines/edge), project y -----------
// z = [g*mean_xt, x_own, g] @ B -> 10 floats; y rows written coalesced (full 64B lines).
__global__ __launch_bounds__(256) void gather_y(
    const float* __restrict__ xt,
    const int* __restrict__ head_c, const int* __restrict__ head_p,
    const int2* __restrict__ cn_m, const int2* __restrict__ pn_i,
    const float* __restrict__ xc, const float* __restrict__ xp,
    const float* __restrict__ B,
    float* __restrict__ y_c, float* __restrict__ y_p) {
  __shared__ float sB[340];   // rows 0..33 of B
  int tid = threadIdx.x;
  for (int i = tid; i < 340; i += 256) sB[i] = B[i];
  __syncthreads();
  int i = blockIdx.x * 256 + tid;
  if (i >= NCV + NPV) return;
  bool isC = i < NCV;
  int idx = isC ? i : i - NCV;
  const int2* nodes = isC ? cn_m : pn_i;
  int e = isC ? head_c[idx] : head_p[idx];

  float acc[8] = {0.f, 0.f, 0.f, 0.f, 0.f, 0.f, 0.f, 0.f};
  float cnt = 0.f;
  while (e >= 0) {
    int2 v = nodes[e];
    const float4* xr = (const float4*)(xt + (size_t)v.y * 8);
    float4 u = xr[0], w = xr[1];
    acc[0] += u.x; acc[1] += u.y; acc[2] += u.z; acc[3] += u.w;
    acc[4] += w.x; acc[5] += w.y; acc[6] += w.z; acc[7] += w.w;
    cnt += 1.f;
    e = v.x;
  }

  const float* xo = (isC ? xc : xp) + (size_t)idx * 8;
  const float* Bs = sB + (isC ? 0 : 170);
  float gg = cnt > 0.f ? 1.f : 0.f;
  float inv = gg / fmaxf(cnt, 1.f);
  float lg[OUTC];
  #pragma unroll
  for (int o = 0; o < OUTC; ++o) lg[o] = gg * Bs[16 * 10 + o];
  #pragma unroll
  for (int r = 0; r < 8; ++r) {
    float zb = acc[r] * inv;
    float zo = xo[r];
    #pragma unroll
    for (int o = 0; o < OUTC; ++o)
      lg[o] += zb * Bs[r * 10 + o] + zo * Bs[(8 + r) * 10 + o];
  }
  float4* yv = (float4*)((isC ? y_c : y_p) + (size_t)idx * YST);
  yv[0] = make_float4(lg[0], lg[1], lg[2], lg[3]);
  yv[1] = make_float4(lg[4], lg[5], lg[6], lg[7]);
  yv[2] = make_float4(lg[8], lg[9], 0.f, 0.f);
  yv[3] = make_float4(0.f, 0.f, 0.f, 0.f);
}

// ---------------- K3: dual interleaved int2 walks + LLC-resident y reads + softmax ----
__global__ __launch_bounds__(256) void gather_t(
    const float* __restrict__ y_c, const float* __restrict__ y_p,
    const float* __restrict__ xt,
    const int* __restrict__ heads_t,
    const int2* __restrict__ tn_m, const int2* __restrict__ tn_i,
    const float* __restrict__ B, float* __restrict__ out) {
  __shared__ float sB[110];   // rows 34..44 of B
  int tid = threadIdx.x;
  for (int i = tid; i < 110; i += 256) sB[i] = B[340 + i];
  __syncthreads();
  int t = blockIdx.x * 256 + tid;
  if (t >= NTV) return;

  int2 ht = ((const int2*)heads_t)[t];   // {makes-head, in-head}, one 8B coalesced load
  int e1 = ht.x, e2 = ht.y;

  float sc[OUTC] = {0.f, 0.f, 0.f, 0.f, 0.f, 0.f, 0.f, 0.f, 0.f, 0.f};
  float sp[OUTC] = {0.f, 0.f, 0.f, 0.f, 0.f, 0.f, 0.f, 0.f, 0.f, 0.f};
  float dc = 0.f, dp = 0.f;
  while (e1 >= 0 || e2 >= 0) {
    if (e1 >= 0) {
      int2 v = tn_m[e1];
      const float* yr = y_c + (size_t)v.y * YST;
      float4 u = *(const float4*)yr;
      float4 w = *(const float4*)(yr + 4);
      float2 z = *(const float2*)(yr + 8);
      sc[0] += u.x; sc[1] += u.y; sc[2] += u.z; sc[3] += u.w;
      sc[4] += w.x; sc[5] += w.y; sc[6] += w.z; sc[7] += w.w;
      sc[8] += z.x; sc[9] += z.y;
      dc += 1.f;
      e1 = v.x;
    }
    if (e2 >= 0) {
      int2 v = tn_i[e2];
      const float* yr = y_p + (size_t)v.y * YST;
      float4 u = *(const float4*)yr;
      float4 w = *(const float4*)(yr + 4);
      float2 z = *(const float2*)(yr + 8);
      sp[0] += u.x; sp[1] += u.y; sp[2] += u.z; sp[3] += u.w;
      sp[4] += w.x; sp[5] += w.y; sp[6] += w.z; sp[7] += w.w;
      sp[8] += z.x; sp[9] += z.y;
      dp += 1.f;
      e2 = v.x;
    }
  }

  float Gc = dc > 0.f ? 1.f : 0.f, Gp = dp > 0.f ? 1.f : 0.f;
  float ivc = 1.f / fmaxf(dc, 1.f), ivp = 1.f / fmaxf(dp, 1.f);

  const float4* xp4 = (const float4*)(xt + (size_t)t * 8);
  float4 xa = xp4[0], xb = xp4[1];
  float xv[8] = {xa.x, xa.y, xa.z, xa.w, xb.x, xb.y, xb.z, xb.w};

  float lg[OUTC];
  #pragma unroll
  for (int o = 0; o < OUTC; ++o)
    lg[o] = sc[o] * ivc + sp[o] * ivp +
            Gc * sB[80 + o] + Gp * sB[90 + o] + sB[100 + o];
  #pragma unroll
  for (int r = 0; r < 8; ++r) {
    float xr = xv[r];
    #pragma unroll
    for (int o = 0; o < OUTC; ++o) lg[o] += xr * sB[r * 10 + o];
  }

  float m = lg[0];
  #pragma unroll
  for (int o = 1; o < OUTC; ++o) m = fmaxf(m, lg[o]);
  float s = 0.f;
  #pragma unroll
  for (int o = 0; o < OUTC; ++o) { lg[o] = __expf(lg[o] - m); s += lg[o]; }
  float invs = 1.0f / s;
  float* op = &out[(size_t)t * OUTC];
  #pragma unroll
  for (int o = 0; o < 5; ++o) {
    float2 p2; p2.x = lg[2 * o] * invs; p2.y = lg[2 * o + 1] * invs;
    *(float2*)&op[2 * o] = p2;
  }
}

extern "C" void kernel_launch(void* const* d_in, const int* in_sizes, int n_in,
                              void* d_out, int out_size, void* d_ws, size_t ws_size,
                              hipStream_t stream) {
  const float* x_c   = (const float*)d_in[0];
  const float* x_t   = (const float*)d_in[1];
  const float* x_p   = (const float*)d_in[2];
  const float* W_col = (const float*)d_in[3];
  const float* b_col = (const float*)d_in[4];
  const float* Wn    = (const float*)d_in[5];
  const float* Wr    = (const float*)d_in[6];
  const float* b_lin = (const float*)d_in[7];
  const float* W_out = (const float*)d_in[8];
  const float* b_out = (const float*)d_in[9];
  const int* e_m_src = (const int*)d_in[10];
  const int* e_m_dst = (const int*)d_in[11];
  const int* e_i_src = (const int*)d_in[12];
  const int* e_i_dst = (const int*)d_in[13];
  float* out = (float*)d_out;

  // ---- workspace carve-out (~27 MB; ws_size = 256 MiB) ----
  size_t cursor = 0;
  char* base = (char*)d_ws;
  auto alloc = [&](size_t bytes) {
    void* p = base + cursor;
    cursor += (bytes + 255) & ~(size_t)255;
    return p;
  };
  int nheads = NCV + NPV + 2 * NTV;
  int* heads   = (int*)alloc((size_t)nheads * 4);                  // 3.0 MB
  int* head_c  = heads;
  int* head_p  = heads + NCV;
  int* heads_t = heads + NCV + NPV;                                // int2-interleaved per t
  int2* cn_m = (int2*)alloc((size_t)EMV * 8);                      // 2.4 MB
  int2* tn_m = (int2*)alloc((size_t)EMV * 8);                      // 2.4 MB
  int2* pn_i = (int2*)alloc((size_t)EIV * 8);                      // 4.8 MB
  int2* tn_i = (int2*)alloc((size_t)EIV * 8);                      // 4.8 MB
  float* y_c = (float*)alloc((size_t)NCV * YST * 4);               // 6.4 MB
  float* y_p = (float*)alloc((size_t)NPV * YST * 4);               // 3.2 MB
  float* T   = (float*)alloc(3 * 1280 * 4);
  float* Q   = (float*)alloc(7 * 1280 * 4);
  float* B   = (float*)alloc(450 * 4);

  const float* Wn_l[2][4]; const float* Wr_l[2][4];
  for (int l = 0; l < 2; ++l)
    for (int r = 0; r < 4; ++r) {
      Wn_l[l][r] = Wn + (size_t)(l * 4 + r) * DD * DD;
      Wr_l[l][r] = Wr + (size_t)(l * 4 + r) * DD * DD;
    }

  // ---- heads init to -1 (3 MB async memset) ----
  hipMemsetAsync(heads, 0xFF, (size_t)nheads * 4, stream);

  // ---- build int2-node lists (atomic floor ~76 us) ----
  build_graph<<<(EIV + 255) / 256, 256, 0, stream>>>(
      e_m_src, e_m_dst, e_i_src, e_i_dst,
      head_c, head_p, heads_t, cn_m, tn_m, pn_i, tn_i);

  // ---- weight folding (wave-per-output; proven-fast r1 kernels) ----
  prep_T_w<<<(3 * 1280 * 64 + 255) / 256, 256, 0, stream>>>(
      Wn_l[1][0], Wn_l[1][2], Wr_l[1][0], Wr_l[1][2], W_out, T);
  prep_Q_w<<<(7 * 1280 * 64 + 255) / 256, 256, 0, stream>>>(
      Wn_l[0][1], Wr_l[0][1], Wn_l[0][3], Wr_l[0][3],
      Wn_l[0][0], Wn_l[0][2], Wr_l[0][0], Wr_l[0][2], T, Q);
  prep_B_w<<<(450 * 64 + 255) / 256, 256, 0, stream>>>(
      W_col, b_col, b_lin, W_out, b_out, T, Q, B);

  // ---- gather x_t over c/p lists + project y ----
  gather_y<<<(NCV + NPV + 255) / 256, 256, 0, stream>>>(
      x_t, head_c, head_p, cn_m, pn_i, x_c, x_p, B, y_c, y_p);

  // ---- gather y over t lists + combine + softmax ----
  gather_t<<<(NTV + 255) / 256, 256, 0, stream>>>(
      y_c, y_p, x_t, heads_t, tn_m, tn_i, B, out);
}